// Round 1
// baseline (1757.738 us; speedup 1.0000x reference)
//
#include <hip/hip_runtime.h>
#include <hip/hip_bf16.h>
#include <stdint.h>

#define N_NODES 100000
#define N_EDGES 1600000
#define MIN_NORM 1e-15f
#define MAXNORM 0.996f          // (1 - 4e-3)/sqrt(1)
#define ART_CLIP 0.9999999f     // 1 - 1e-7

__device__ __forceinline__ float wsum(float v) {
#pragma unroll
    for (int m = 32; m >= 1; m >>= 1) v += __shfl_xor(v, m, 64);
    return v;
}

__device__ __forceinline__ float artanh_f(float x) {
    x = fminf(fmaxf(x, -ART_CLIP), ART_CLIP);
    return 0.5f * (log1pf(x) - log1pf(-x));
}

// ---------------- CSR build ----------------
__global__ void k_hist(const int* __restrict__ dst, unsigned* __restrict__ cur, int E) {
    int e = blockIdx.x * blockDim.x + threadIdx.x;
    if (e < E) atomicAdd(&cur[dst[e]], 1u);
}

__global__ void k_scan(unsigned* __restrict__ cur, unsigned* __restrict__ off, int n) {
    __shared__ unsigned part[1024];
    const int t = threadIdx.x;
    const int C = (n + 1023) / 1024;
    int lo = t * C, hi = min(lo + C, n);
    unsigned s = 0;
    for (int i = lo; i < hi; ++i) s += cur[i];
    part[t] = s;
    __syncthreads();
    if (t == 0) {
        unsigned run = 0;
        for (int k = 0; k < 1024; ++k) { unsigned tmp = part[k]; part[k] = run; run += tmp; }
        off[n] = run;
    }
    __syncthreads();
    unsigned run = part[t];
    for (int i = lo; i < hi; ++i) { unsigned c = cur[i]; off[i] = run; cur[i] = run; run += c; }
}

__global__ void k_fill(const int* __restrict__ dst, unsigned* __restrict__ cur,
                       unsigned* __restrict__ perm, int E) {
    int e = blockIdx.x * blockDim.x + threadIdx.x;
    if (e < E) { unsigned slot = atomicAdd(&cur[dst[e]], 1u); perm[slot] = (unsigned)e; }
}

// ---------------- hyperbolic bias: hb = proj(expmap0(b)), hb[64] = ||hb||^2 ----
__global__ void k_hb(const float* __restrict__ b, float* __restrict__ hb) {
    int lane = threadIdx.x & 63;
    float u = b[lane];
    float n = sqrtf(fmaxf(wsum(u * u), MIN_NORM));
    float t = tanhf(n);
    float h = t * u / n;
    float hn = sqrtf(fmaxf(wsum(h * h), MIN_NORM));
    if (hn > MAXNORM) h *= MAXNORM / hn;
    hb[lane] = h;
    float y2 = wsum(h * h);
    if (lane == 0) hb[64] = y2;
}

// post-matvec tail: proj(mobius_matvec result) -> mobius_add(hb) -> proj -> logmap0
__device__ __forceinline__ float post_linear(float mxv, float xn, const float* shb, int lane) {
    float mxn = sqrtf(fmaxf(wsum(mxv * mxv), MIN_NORM));
    float at = artanh_f(xn);
    float res = tanhf(mxn / xn * at) * mxv / mxn;
    // proj
    float rn = sqrtf(fmaxf(wsum(res * res), MIN_NORM));
    if (rn > MAXNORM) res *= MAXNORM / rn;
    // mobius_add(res, hb)
    float hbv = shb[lane];
    float y2 = shb[64];
    float xy = wsum(res * hbv);
    float x2 = wsum(res * res);
    float num = (1.f + 2.f * xy + y2) * res + (1.f - x2) * hbv;
    float den = 1.f + 2.f * xy + x2 * y2;
    float o = num / fmaxf(den, MIN_NORM);
    // proj
    float on = sqrtf(fmaxf(wsum(o * o), MIN_NORM));
    if (on > MAXNORM) { o *= MAXNORM / on; on = MAXNORM; }
    // logmap0
    return artanh_f(on) * o / on;
}

// fused: [encode ->] mobius_matvec(W) -> +hyp_b -> proj -> logmap0, 4 nodes/wave
template <bool ENCODE>
__global__ void __launch_bounds__(256) k_lin(const float* __restrict__ xin,
                                             const float* __restrict__ W,
                                             const float* __restrict__ hb,
                                             float* __restrict__ xt_out, int nNodes) {
    __shared__ float wt[4096];   // wt[j*64 + o] = W[o*64 + j]
    __shared__ float shb[65];
    for (int i = threadIdx.x; i < 4096; i += blockDim.x) {
        int o = i >> 6, j = i & 63;
        wt[j * 64 + o] = W[i];
    }
    if (threadIdx.x < 65) shb[threadIdx.x] = hb[threadIdx.x];
    __syncthreads();
    const int lane = threadIdx.x & 63, wid = threadIdx.x >> 6;
    const int gw = blockIdx.x * (blockDim.x >> 6) + wid;
    const int nw = gridDim.x * (blockDim.x >> 6);
    for (int base = gw * 4; base < nNodes; base += nw * 4) {
        const int cnt = min(4, nNodes - base);
        float u[4], xn[4], mx[4];
#pragma unroll
        for (int k = 0; k < 4; ++k)
            u[k] = (k < cnt) ? xin[(size_t)(base + k) * 64 + lane] : 0.f;
        if (ENCODE) {
#pragma unroll
            for (int k = 0; k < 4; ++k) {
                float n = sqrtf(fmaxf(wsum(u[k] * u[k]), MIN_NORM));
                float t = tanhf(n);
                float h = t * u[k] / n;
                float hn = sqrtf(fmaxf(wsum(h * h), MIN_NORM));
                if (hn > MAXNORM) h *= MAXNORM / hn;
                u[k] = h;
            }
        }
#pragma unroll
        for (int k = 0; k < 4; ++k)
            xn[k] = sqrtf(fmaxf(wsum(u[k] * u[k]), MIN_NORM));
        mx[0] = mx[1] = mx[2] = mx[3] = 0.f;
#pragma unroll
        for (int j = 0; j < 64; ++j) {
            float wv = wt[j * 64 + lane];
            mx[0] = fmaf(wv, __shfl(u[0], j, 64), mx[0]);
            mx[1] = fmaf(wv, __shfl(u[1], j, 64), mx[1]);
            mx[2] = fmaf(wv, __shfl(u[2], j, 64), mx[2]);
            mx[3] = fmaf(wv, __shfl(u[3], j, 64), mx[3]);
        }
#pragma unroll
        for (int k = 0; k < 4; ++k) {
            if (k < cnt) {
                float xt = post_linear(mx[k], xn[k], shb, lane);
                xt_out[(size_t)(base + k) * 64 + lane] = xt;
            }
        }
    }
}

// CSR gather-aggregate + expmap0/proj + relu(logmap0) + expmap0/proj
__global__ void __launch_bounds__(256) k_agg(const float* __restrict__ xt,
                                             const int* __restrict__ src,
                                             const float* __restrict__ w,
                                             const unsigned* __restrict__ off,
                                             const unsigned* __restrict__ perm,
                                             float* __restrict__ hout, int nNodes) {
    const int lane = threadIdx.x & 63, wid = threadIdx.x >> 6;
    int gw = blockIdx.x * (blockDim.x >> 6) + wid;
    int nw = gridDim.x * (blockDim.x >> 6);
    for (int node = gw; node < nNodes; node += nw) {
        unsigned s0 = off[node], s1 = off[node + 1];
        float acc = 0.f;
        for (unsigned k = s0; k < s1; ++k) {
            unsigned e = perm[k];
            float we = w[e];
            int sn = src[e];
            acc = fmaf(xt[(size_t)sn * 64 + lane], we, acc);
        }
        // expmap0 + proj
        float n = sqrtf(fmaxf(wsum(acc * acc), MIN_NORM));
        float t = tanhf(n);
        float p = t * acc / n;
        float pn = sqrtf(fmaxf(wsum(p * p), MIN_NORM));
        if (pn > MAXNORM) { p *= MAXNORM / pn; pn = MAXNORM; }
        // hyp_act: relu in tangent space
        float xv = artanh_f(pn) * p / pn;
        xv = fmaxf(xv, 0.f);
        // expmap0 + proj
        float m = sqrtf(fmaxf(wsum(xv * xv), MIN_NORM));
        float t2 = tanhf(m);
        float q = t2 * xv / m;
        float qn = sqrtf(fmaxf(wsum(q * q), MIN_NORM));
        if (qn > MAXNORM) q *= MAXNORM / qn;
        hout[(size_t)node * 64 + lane] = q;
    }
}

extern "C" void kernel_launch(void* const* d_in, const int* in_sizes, int n_in,
                              void* d_out, int out_size, void* d_ws, size_t ws_size,
                              hipStream_t stream) {
    const float* x   = (const float*)d_in[0];
    const int*   ei  = (const int*)d_in[1];
    const float* ew  = (const float*)d_in[2];
    const float* W0  = (const float*)d_in[3];
    const float* b0  = (const float*)d_in[4];
    const float* W1  = (const float*)d_in[5];
    const float* b1  = (const float*)d_in[6];
    const int N = in_sizes[0] / 64;
    const int E = in_sizes[2];
    const int* src = ei;
    const int* dst = ei + E;

    // workspace carve (256B aligned)
    uint8_t* p = (uint8_t*)d_ws;
    auto carve = [&](size_t bytes) { uint8_t* q = p; p += (bytes + 255) & ~(size_t)255; return q; };
    unsigned* off  = (unsigned*)carve((size_t)(N + 1) * 4);
    unsigned* cur  = (unsigned*)carve((size_t)N * 4);
    unsigned* perm = (unsigned*)carve((size_t)E * 4);
    float* hb0 = (float*)carve(65 * 4);
    float* hb1 = (float*)carve(65 * 4);
    float* xt  = (float*)carve((size_t)N * 64 * 4);
    float* hbuf = (float*)d_out;   // reuse output buffer as inter-layer h

    // CSR build
    hipMemsetAsync(cur, 0, (size_t)N * 4, stream);
    k_hist<<<(E + 255) / 256, 256, 0, stream>>>(dst, cur, E);
    k_scan<<<1, 1024, 0, stream>>>(cur, off, N);
    k_fill<<<(E + 255) / 256, 256, 0, stream>>>(dst, cur, perm, E);

    // hyperbolic biases
    k_hb<<<1, 64, 0, stream>>>(b0, hb0);
    k_hb<<<1, 64, 0, stream>>>(b1, hb1);

    const int linBlocks = (N + 15) / 16;   // 4 waves * 4 nodes per block
    // layer 0
    k_lin<true><<<linBlocks, 256, 0, stream>>>(x, W0, hb0, xt, N);
    k_agg<<<2048, 256, 0, stream>>>(xt, src, ew, off, perm, hbuf, N);
    // layer 1
    k_lin<false><<<linBlocks, 256, 0, stream>>>(hbuf, W1, hb1, xt, N);
    k_agg<<<2048, 256, 0, stream>>>(xt, src, ew, off, perm, (float*)d_out, N);
}

// Round 2
// 967.330 us; speedup vs baseline: 1.8171x; 1.8171x over previous
//
#include <hip/hip_runtime.h>
#include <hip/hip_bf16.h>
#include <stdint.h>

#define MIN_NORM 1e-15f
#define MAXNORM 0.996f          // (1 - 4e-3)/sqrt(1)
#define ART_CLIP 0.9999999f     // 1 - 1e-7

__device__ __forceinline__ float wsum(float v) {
#pragma unroll
    for (int m = 32; m >= 1; m >>= 1) v += __shfl_xor(v, m, 64);
    return v;
}

__device__ __forceinline__ float artanh_f(float x) {
    x = fminf(fmaxf(x, -ART_CLIP), ART_CLIP);
    return 0.5f * (log1pf(x) - log1pf(-x));
}

__device__ __forceinline__ float lane_bcast(float v, int j) {
    return __builtin_bit_cast(float, __builtin_amdgcn_readlane(__builtin_bit_cast(int, v), j));
}

// ---------------- CSR build ----------------
__global__ void k_hist(const int* __restrict__ dst, unsigned* __restrict__ cur, int E) {
    int e = blockIdx.x * blockDim.x + threadIdx.x;
    if (e < E) atomicAdd(&cur[dst[e]], 1u);
}

__global__ void k_scan(unsigned* __restrict__ cur, unsigned* __restrict__ off, int n) {
    __shared__ unsigned part[1024];
    const int t = threadIdx.x;
    const int C = (n + 1023) / 1024;
    int lo = t * C, hi = min(lo + C, n);
    unsigned s = 0;
    for (int i = lo; i < hi; ++i) s += cur[i];
    part[t] = s;
    __syncthreads();
    if (t == 0) {
        unsigned run = 0;
        for (int k = 0; k < 1024; ++k) { unsigned tmp = part[k]; part[k] = run; run += tmp; }
        off[n] = run;
    }
    __syncthreads();
    unsigned run = part[t];
    for (int i = lo; i < hi; ++i) { unsigned c = cur[i]; off[i] = run; cur[i] = run; run += c; }
}

// fill sorted-by-dst edge arrays directly (removes perm indirection in k_agg)
__global__ void k_fill(const int* __restrict__ dst, const int* __restrict__ src,
                       const float* __restrict__ ew, unsigned* __restrict__ cur,
                       int* __restrict__ srcs, float* __restrict__ wse, int E) {
    int e = blockIdx.x * blockDim.x + threadIdx.x;
    if (e < E) {
        unsigned slot = atomicAdd(&cur[dst[e]], 1u);
        srcs[slot] = src[e];
        wse[slot]  = ew[e];
    }
}

// ---------------- hyperbolic bias: hb = proj(expmap0(b)), hb[64] = ||hb||^2 ----
__global__ void k_hb(const float* __restrict__ b, float* __restrict__ hb) {
    int lane = threadIdx.x & 63;
    float u = b[lane];
    float n = sqrtf(fmaxf(wsum(u * u), MIN_NORM));
    float t = tanhf(n);
    float h = t * u / n;
    float hn = sqrtf(fmaxf(wsum(h * h), MIN_NORM));
    if (hn > MAXNORM) h *= MAXNORM / hn;
    hb[lane] = h;
    float y2 = wsum(h * h);
    if (lane == 0) hb[64] = y2;
}

// post-matvec tail: proj(mobius_matvec result) -> mobius_add(hb) -> proj -> logmap0
// 3 cross-lane reductions total (mxn, xy, on); rn/x2 come from analytic norms.
__device__ __forceinline__ float post_linear(float mxv, float xn, float hbv, float y2) {
    float mxn = sqrtf(fmaxf(wsum(mxv * mxv), MIN_NORM));
    float at = artanh_f(xn);
    float tt = tanhf(mxn / xn * at);          // = ||res||, in [0,1)
    float res = tt * mxv / mxn;
    float rn = tt;
    if (rn > MAXNORM) { res *= MAXNORM / rn; rn = MAXNORM; }
    float x2 = rn * rn;
    // mobius_add(res, hb)
    float xy = wsum(res * hbv);
    float num = (1.f + 2.f * xy + y2) * res + (1.f - x2) * hbv;
    float den = 1.f + 2.f * xy + x2 * y2;
    float o = num / fmaxf(den, MIN_NORM);
    // proj + logmap0
    float on = sqrtf(fmaxf(wsum(o * o), MIN_NORM));
    if (on > MAXNORM) { o *= MAXNORM / on; on = MAXNORM; }
    return artanh_f(on) * o / on;
}

// fused: [encode ->] mobius_matvec(W) -> +hyp_b -> proj -> logmap0
// readlane matvec: wreg[j] = W[lane][j]; mx[lane] += readlane(u, j) * wreg[j]
template <bool ENCODE>
__global__ void __launch_bounds__(256, 4) k_lin(const float* __restrict__ xin,
                                                const float* __restrict__ W,
                                                const float* __restrict__ hb,
                                                float* __restrict__ xt_out, int nNodes) {
    const int lane = threadIdx.x & 63, wid = threadIdx.x >> 6;
    // per-lane W row into registers (16 KB total, L2-hot after first block)
    float wreg[64];
    {
        const float4* wr = (const float4*)(W + (size_t)lane * 64);
#pragma unroll
        for (int q = 0; q < 16; ++q) {
            float4 v = wr[q];
            wreg[q * 4 + 0] = v.x; wreg[q * 4 + 1] = v.y;
            wreg[q * 4 + 2] = v.z; wreg[q * 4 + 3] = v.w;
        }
    }
    const float hbv = hb[lane];
    const float y2  = hb[64];

    const int gw = blockIdx.x * 4 + wid;
    const int nw = gridDim.x * 4;
    for (int base = gw * 2; base < nNodes; base += nw * 2) {
        const bool has1 = (base + 1) < nNodes;
        float u0 = xin[(size_t)base * 64 + lane];
        float u1 = has1 ? xin[(size_t)(base + 1) * 64 + lane] : 0.f;
        float xn0, xn1;
        if (ENCODE) {
            // encode: proj(expmap0(u)); ||expmap0(u)|| = tanh(||u||) analytically
            float n0 = sqrtf(fmaxf(wsum(u0 * u0), MIN_NORM));
            float n1 = sqrtf(fmaxf(wsum(u1 * u1), MIN_NORM));
            float t0 = tanhf(n0), t1 = tanhf(n1);
            u0 = t0 * u0 / n0;
            u1 = t1 * u1 / n1;
            if (t0 > MAXNORM) { u0 *= MAXNORM / t0; t0 = MAXNORM; }
            if (t1 > MAXNORM) { u1 *= MAXNORM / t1; t1 = MAXNORM; }
            xn0 = t0; xn1 = t1;
        } else {
            xn0 = sqrtf(fmaxf(wsum(u0 * u0), MIN_NORM));
            xn1 = sqrtf(fmaxf(wsum(u1 * u1), MIN_NORM));
        }
        // readlane matvec, 2 accumulator chains per node
        float a0e = 0.f, a0o = 0.f, a1e = 0.f, a1o = 0.f;
#pragma unroll
        for (int j = 0; j < 64; j += 2) {
            a0e = fmaf(lane_bcast(u0, j),     wreg[j],     a0e);
            a0o = fmaf(lane_bcast(u0, j + 1), wreg[j + 1], a0o);
            a1e = fmaf(lane_bcast(u1, j),     wreg[j],     a1e);
            a1o = fmaf(lane_bcast(u1, j + 1), wreg[j + 1], a1o);
        }
        float mx0 = a0e + a0o, mx1 = a1e + a1o;
        xt_out[(size_t)base * 64 + lane] = post_linear(mx0, xn0, hbv, y2);
        if (has1)
            xt_out[(size_t)(base + 1) * 64 + lane] = post_linear(mx1, xn1, hbv, y2);
    }
}

// CSR gather-aggregate + expmap0/proj + relu(logmap0) + expmap0/proj (2 wsums)
__global__ void __launch_bounds__(256) k_agg(const float* __restrict__ xt,
                                             const int* __restrict__ srcs,
                                             const float* __restrict__ wse,
                                             const unsigned* __restrict__ off,
                                             float* __restrict__ hout, int nNodes) {
    const int lane = threadIdx.x & 63, wid = threadIdx.x >> 6;
    int gw = blockIdx.x * (blockDim.x >> 6) + wid;
    int nw = gridDim.x * (blockDim.x >> 6);
    for (int node = gw; node < nNodes; node += nw) {
        unsigned s0 = off[node], s1 = off[node + 1];
        float acc = 0.f;
        for (unsigned k = s0; k < s1; ++k) {
            int sn = srcs[k];
            float we = wse[k];
            acc = fmaf(xt[(size_t)sn * 64 + lane], we, acc);
        }
        // expmap0 + proj (norm after scaling = tanh(n))
        float n = sqrtf(fmaxf(wsum(acc * acc), MIN_NORM));
        float t = tanhf(n);
        float p = t * acc / n;
        float pn = t;
        if (pn > MAXNORM) { p *= MAXNORM / pn; pn = MAXNORM; }
        // hyp_act: relu in tangent space
        float xv = artanh_f(pn) * p / pn;
        xv = fmaxf(xv, 0.f);
        // expmap0 + proj (norm = tanh(m))
        float m = sqrtf(fmaxf(wsum(xv * xv), MIN_NORM));
        float t2 = tanhf(m);
        float q = t2 * xv / m;
        float qn = t2;
        if (qn > MAXNORM) q *= MAXNORM / qn;
        hout[(size_t)node * 64 + lane] = q;
    }
}

extern "C" void kernel_launch(void* const* d_in, const int* in_sizes, int n_in,
                              void* d_out, int out_size, void* d_ws, size_t ws_size,
                              hipStream_t stream) {
    const float* x   = (const float*)d_in[0];
    const int*   ei  = (const int*)d_in[1];
    const float* ew  = (const float*)d_in[2];
    const float* W0  = (const float*)d_in[3];
    const float* b0  = (const float*)d_in[4];
    const float* W1  = (const float*)d_in[5];
    const float* b1  = (const float*)d_in[6];
    const int N = in_sizes[0] / 64;
    const int E = in_sizes[2];
    const int* src = ei;
    const int* dst = ei + E;

    // workspace carve (256B aligned)
    uint8_t* p = (uint8_t*)d_ws;
    auto carve = [&](size_t bytes) { uint8_t* q = p; p += (bytes + 255) & ~(size_t)255; return q; };
    unsigned* off  = (unsigned*)carve((size_t)(N + 1) * 4);
    unsigned* cur  = (unsigned*)carve((size_t)N * 4);
    int*      srcs = (int*)carve((size_t)E * 4);
    float*    wse  = (float*)carve((size_t)E * 4);
    float* hb0 = (float*)carve(65 * 4);
    float* hb1 = (float*)carve(65 * 4);
    float* xt  = (float*)carve((size_t)N * 64 * 4);
    float* hbuf = (float*)d_out;   // reuse output buffer as inter-layer h

    // CSR build (sorted-by-dst src/weight arrays)
    hipMemsetAsync(cur, 0, (size_t)N * 4, stream);
    k_hist<<<(E + 255) / 256, 256, 0, stream>>>(dst, cur, E);
    k_scan<<<1, 1024, 0, stream>>>(cur, off, N);
    k_fill<<<(E + 255) / 256, 256, 0, stream>>>(dst, src, ew, cur, srcs, wse, E);

    // hyperbolic biases
    k_hb<<<1, 64, 0, stream>>>(b0, hb0);
    k_hb<<<1, 64, 0, stream>>>(b1, hb1);

    // layer 0
    k_lin<true><<<2048, 256, 0, stream>>>(x, W0, hb0, xt, N);
    k_agg<<<2048, 256, 0, stream>>>(xt, srcs, wse, off, hbuf, N);
    // layer 1
    k_lin<false><<<2048, 256, 0, stream>>>(hbuf, W1, hb1, xt, N);
    k_agg<<<2048, 256, 0, stream>>>(xt, srcs, wse, off, (float*)d_out, N);
}

// Round 3
// 742.625 us; speedup vs baseline: 2.3669x; 1.3026x over previous
//
#include <hip/hip_runtime.h>
#include <hip/hip_bf16.h>
#include <stdint.h>

#define MIN_NORM 1e-15f
#define MAXNORM 0.996f          // (1 - 4e-3)/sqrt(1)
#define ART_CLIP 0.9999999f     // 1 - 1e-7

__device__ __forceinline__ float wsum(float v) {
#pragma unroll
    for (int m = 32; m >= 1; m >>= 1) v += __shfl_xor(v, m, 64);
    return v;
}

__device__ __forceinline__ unsigned wsum_u(unsigned v) {
#pragma unroll
    for (int m = 32; m >= 1; m >>= 1) v += __shfl_xor(v, m, 64);
    return v;
}

__device__ __forceinline__ unsigned wave_iscan(unsigned v, int lane) {
#pragma unroll
    for (int d = 1; d < 64; d <<= 1) {
        unsigned o = __shfl_up(v, d, 64);
        if (lane >= d) v += o;
    }
    return v;
}

__device__ __forceinline__ float artanh_f(float x) {
    x = fminf(fmaxf(x, -ART_CLIP), ART_CLIP);
    return 0.5f * (log1pf(x) - log1pf(-x));
}

__device__ __forceinline__ float lane_bcast(float v, int j) {
    return __builtin_bit_cast(float, __builtin_amdgcn_readlane(__builtin_bit_cast(int, v), j));
}

// ---------------- CSR build ----------------
__global__ void k_hist(const int* __restrict__ dst, unsigned* __restrict__ cur, int E) {
    int e = blockIdx.x * blockDim.x + threadIdx.x;
    if (e < E) atomicAdd(&cur[dst[e]], 1u);
}

// 3-pass hierarchical exclusive scan of cur[0..n) -> off[0..n], cur := off copy
#define SCAN_B 256
__global__ void __launch_bounds__(256) k_scanA(const unsigned* __restrict__ cur,
                                               unsigned* __restrict__ bsum, int n, int chunk) {
    const int lo = blockIdx.x * chunk, hi = min(lo + chunk, n);
    unsigned s = 0;
    for (int i = lo + threadIdx.x; i < hi; i += 256) s += cur[i];
    __shared__ unsigned wpart[4];
    const int lane = threadIdx.x & 63, wid = threadIdx.x >> 6;
    s = wsum_u(s);
    if (lane == 0) wpart[wid] = s;
    __syncthreads();
    if (threadIdx.x == 0) bsum[blockIdx.x] = wpart[0] + wpart[1] + wpart[2] + wpart[3];
}

__global__ void __launch_bounds__(256) k_scanB(unsigned* __restrict__ bsum,
                                               unsigned* __restrict__ off, int n) {
    __shared__ unsigned wpart[4];
    const int t = threadIdx.x, lane = t & 63, wid = t >> 6;
    unsigned v = bsum[t];
    unsigned inc = wave_iscan(v, lane);
    if (lane == 63) wpart[wid] = inc;
    __syncthreads();
    unsigned wo = 0;
    for (int i = 0; i < wid; ++i) wo += wpart[i];
    bsum[t] = wo + inc - v;                 // exclusive prefix
    if (t == 255) off[n] = wo + inc;        // grand total
}

__global__ void __launch_bounds__(256) k_scanC(unsigned* __restrict__ cur,
                                               const unsigned* __restrict__ bsum,
                                               unsigned* __restrict__ off, int n, int chunk) {
    const int lo = blockIdx.x * chunk, hi = min(lo + chunk, n);
    const int t = threadIdx.x, lane = t & 63, wid = t >> 6;
    const int S = (chunk + 255) >> 8;       // <=4 for N<=262144
    const int a = lo + t * S, b = min(a + S, hi);
    unsigned c[4];
    unsigned segsum = 0;
#pragma unroll
    for (int s = 0; s < 4; ++s) {
        int i = a + s;
        unsigned v = (s < S && i < b) ? cur[i] : 0u;
        c[s] = v; segsum += v;
    }
    __shared__ unsigned wpart[4];
    unsigned inc = wave_iscan(segsum, lane);
    if (lane == 63) wpart[wid] = inc;
    __syncthreads();
    unsigned wo = 0;
    for (int i = 0; i < wid; ++i) wo += wpart[i];
    unsigned run = bsum[blockIdx.x] + wo + inc - segsum;
#pragma unroll
    for (int s = 0; s < 4; ++s) {
        int i = a + s;
        if (s < S && i < b) { off[i] = run; cur[i] = run; run += c[s]; }
    }
}

// fill sorted-by-dst edge arrays directly
__global__ void k_fill(const int* __restrict__ dst, const int* __restrict__ src,
                       const float* __restrict__ ew, unsigned* __restrict__ cur,
                       int* __restrict__ srcs, float* __restrict__ wse, int E) {
    int e = blockIdx.x * blockDim.x + threadIdx.x;
    if (e < E) {
        unsigned slot = atomicAdd(&cur[dst[e]], 1u);
        srcs[slot] = src[e];
        wse[slot]  = ew[e];
    }
}

// ---------------- hyperbolic biases (both in one launch) ----------------
__global__ void k_hb2(const float* __restrict__ b0, float* __restrict__ hb0,
                      const float* __restrict__ b1, float* __restrict__ hb1) {
    const float* b  = blockIdx.x ? b1 : b0;
    float* hb       = blockIdx.x ? hb1 : hb0;
    int lane = threadIdx.x & 63;
    float u = b[lane];
    float n = sqrtf(fmaxf(wsum(u * u), MIN_NORM));
    float t = tanhf(n);
    float h = t * u / n;
    float hn = sqrtf(fmaxf(wsum(h * h), MIN_NORM));
    if (hn > MAXNORM) h *= MAXNORM / hn;
    hb[lane] = h;
    float y2 = wsum(h * h);
    if (lane == 0) hb[64] = y2;
}

// post-matvec tail: proj(mobius_matvec) -> mobius_add(hb) -> proj -> logmap0
__device__ __forceinline__ float post_linear(float mxv, float xn, float hbv, float y2) {
    float mxn = sqrtf(fmaxf(wsum(mxv * mxv), MIN_NORM));
    float at = artanh_f(xn);
    float tt = tanhf(mxn / xn * at);          // = ||res||
    float res = tt * mxv / mxn;
    float rn = tt;
    if (rn > MAXNORM) { res *= MAXNORM / rn; rn = MAXNORM; }
    float x2 = rn * rn;
    float xy = wsum(res * hbv);
    float num = (1.f + 2.f * xy + y2) * res + (1.f - x2) * hbv;
    float den = 1.f + 2.f * xy + x2 * y2;
    float o = num / fmaxf(den, MIN_NORM);
    float on = sqrtf(fmaxf(wsum(o * o), MIN_NORM));
    if (on > MAXNORM) { o *= MAXNORM / on; on = MAXNORM; }
    return artanh_f(on) * o / on;
}

// fused: [encode ->] mobius_matvec(W) -> +hyp_b -> proj -> logmap0
template <bool ENCODE>
__global__ void __launch_bounds__(256, 4) k_lin(const float* __restrict__ xin,
                                                const float* __restrict__ W,
                                                const float* __restrict__ hb,
                                                float* __restrict__ xt_out, int nNodes) {
    const int lane = threadIdx.x & 63, wid = threadIdx.x >> 6;
    float wreg[64];
    {
        const float4* wr = (const float4*)(W + (size_t)lane * 64);
#pragma unroll
        for (int q = 0; q < 16; ++q) {
            float4 v = wr[q];
            wreg[q * 4 + 0] = v.x; wreg[q * 4 + 1] = v.y;
            wreg[q * 4 + 2] = v.z; wreg[q * 4 + 3] = v.w;
        }
    }
    const float hbv = hb[lane];
    const float y2  = hb[64];

    const int gw = blockIdx.x * 4 + wid;
    const int nw = gridDim.x * 4;
    for (int base = gw * 2; base < nNodes; base += nw * 2) {
        const bool has1 = (base + 1) < nNodes;
        float u0 = xin[(size_t)base * 64 + lane];
        float u1 = has1 ? xin[(size_t)(base + 1) * 64 + lane] : 0.f;
        float xn0, xn1;
        if (ENCODE) {
            float n0 = sqrtf(fmaxf(wsum(u0 * u0), MIN_NORM));
            float n1 = sqrtf(fmaxf(wsum(u1 * u1), MIN_NORM));
            float t0 = tanhf(n0), t1 = tanhf(n1);
            u0 = t0 * u0 / n0;
            u1 = t1 * u1 / n1;
            if (t0 > MAXNORM) { u0 *= MAXNORM / t0; t0 = MAXNORM; }
            if (t1 > MAXNORM) { u1 *= MAXNORM / t1; t1 = MAXNORM; }
            xn0 = t0; xn1 = t1;
        } else {
            xn0 = sqrtf(fmaxf(wsum(u0 * u0), MIN_NORM));
            xn1 = sqrtf(fmaxf(wsum(u1 * u1), MIN_NORM));
        }
        float a0e = 0.f, a0o = 0.f, a1e = 0.f, a1o = 0.f;
#pragma unroll
        for (int j = 0; j < 64; j += 2) {
            a0e = fmaf(lane_bcast(u0, j),     wreg[j],     a0e);
            a0o = fmaf(lane_bcast(u0, j + 1), wreg[j + 1], a0o);
            a1e = fmaf(lane_bcast(u1, j),     wreg[j],     a1e);
            a1o = fmaf(lane_bcast(u1, j + 1), wreg[j + 1], a1o);
        }
        float mx0 = a0e + a0o, mx1 = a1e + a1o;
        xt_out[(size_t)base * 64 + lane] = post_linear(mx0, xn0, hbv, y2);
        if (has1)
            xt_out[(size_t)(base + 1) * 64 + lane] = post_linear(mx1, xn1, hbv, y2);
    }
}

// CSR gather-aggregate + expmap0/proj + relu(logmap0) + expmap0/proj
__global__ void __launch_bounds__(256) k_agg(const float* __restrict__ xt,
                                             const int* __restrict__ srcs,
                                             const float* __restrict__ wse,
                                             const unsigned* __restrict__ off,
                                             float* __restrict__ hout, int nNodes) {
    const int lane = threadIdx.x & 63, wid = threadIdx.x >> 6;
    int gw = blockIdx.x * (blockDim.x >> 6) + wid;
    int nw = gridDim.x * (blockDim.x >> 6);
    for (int node = gw; node < nNodes; node += nw) {
        unsigned s0 = off[node], s1 = off[node + 1];
        float acc = 0.f;
        for (unsigned k = s0; k < s1; ++k) {
            int sn = srcs[k];
            float we = wse[k];
            acc = fmaf(xt[(size_t)sn * 64 + lane], we, acc);
        }
        float n = sqrtf(fmaxf(wsum(acc * acc), MIN_NORM));
        float t = tanhf(n);
        float p = t * acc / n;
        float pn = t;
        if (pn > MAXNORM) { p *= MAXNORM / pn; pn = MAXNORM; }
        float xv = artanh_f(pn) * p / pn;
        xv = fmaxf(xv, 0.f);
        float m = sqrtf(fmaxf(wsum(xv * xv), MIN_NORM));
        float t2 = tanhf(m);
        float q = t2 * xv / m;
        float qn = t2;
        if (qn > MAXNORM) q *= MAXNORM / qn;
        hout[(size_t)node * 64 + lane] = q;
    }
}

extern "C" void kernel_launch(void* const* d_in, const int* in_sizes, int n_in,
                              void* d_out, int out_size, void* d_ws, size_t ws_size,
                              hipStream_t stream) {
    const float* x   = (const float*)d_in[0];
    const int*   ei  = (const int*)d_in[1];
    const float* ew  = (const float*)d_in[2];
    const float* W0  = (const float*)d_in[3];
    const float* b0  = (const float*)d_in[4];
    const float* W1  = (const float*)d_in[5];
    const float* b1  = (const float*)d_in[6];
    const int N = in_sizes[0] / 64;
    const int E = in_sizes[2];
    const int* src = ei;
    const int* dst = ei + E;

    uint8_t* p = (uint8_t*)d_ws;
    auto carve = [&](size_t bytes) { uint8_t* q = p; p += (bytes + 255) & ~(size_t)255; return q; };
    unsigned* off  = (unsigned*)carve((size_t)(N + 1) * 4);
    unsigned* cur  = (unsigned*)carve((size_t)N * 4);
    unsigned* bsum = (unsigned*)carve((size_t)SCAN_B * 4);
    int*      srcs = (int*)carve((size_t)E * 4);
    float*    wse  = (float*)carve((size_t)E * 4);
    float* hb0 = (float*)carve(65 * 4);
    float* hb1 = (float*)carve(65 * 4);
    float* xt  = (float*)carve((size_t)N * 64 * 4);
    float* hbuf = (float*)d_out;

    const int chunk = (N + SCAN_B - 1) / SCAN_B;

    // CSR build (sorted-by-dst src/weight arrays)
    hipMemsetAsync(cur, 0, (size_t)N * 4, stream);
    k_hist<<<(E + 255) / 256, 256, 0, stream>>>(dst, cur, E);
    k_scanA<<<SCAN_B, 256, 0, stream>>>(cur, bsum, N, chunk);
    k_scanB<<<1, 256, 0, stream>>>(bsum, off, N);
    k_scanC<<<SCAN_B, 256, 0, stream>>>(cur, bsum, off, N, chunk);
    k_fill<<<(E + 255) / 256, 256, 0, stream>>>(dst, src, ew, cur, srcs, wse, E);

    k_hb2<<<2, 64, 0, stream>>>(b0, hb0, b1, hb1);

    // layer 0
    k_lin<true><<<2048, 256, 0, stream>>>(x, W0, hb0, xt, N);
    k_agg<<<2048, 256, 0, stream>>>(xt, srcs, wse, off, hbuf, N);
    // layer 1
    k_lin<false><<<2048, 256, 0, stream>>>(hbuf, W1, hb1, xt, N);
    k_agg<<<2048, 256, 0, stream>>>(xt, srcs, wse, off, (float*)d_out, N);
}

// Round 4
// 620.973 us; speedup vs baseline: 2.8306x; 1.1959x over previous
//
#include <hip/hip_runtime.h>
#include <hip/hip_bf16.h>
#include <stdint.h>

#define MIN_NORM 1e-15f
#define MAXNORM 0.996f          // (1 - 4e-3)/sqrt(1)
#define ART_CLIP 0.9999999f     // 1 - 1e-7

__device__ __forceinline__ float wsum(float v) {
#pragma unroll
    for (int m = 32; m >= 1; m >>= 1) v += __shfl_xor(v, m, 64);
    return v;
}

__device__ __forceinline__ unsigned wsum_u(unsigned v) {
#pragma unroll
    for (int m = 32; m >= 1; m >>= 1) v += __shfl_xor(v, m, 64);
    return v;
}

__device__ __forceinline__ unsigned wave_iscan(unsigned v, int lane) {
#pragma unroll
    for (int d = 1; d < 64; d <<= 1) {
        unsigned o = __shfl_up(v, d, 64);
        if (lane >= d) v += o;
    }
    return v;
}

__device__ __forceinline__ float artanh_f(float x) {
    x = fminf(fmaxf(x, -ART_CLIP), ART_CLIP);
    return 0.5f * (log1pf(x) - log1pf(-x));
}

__device__ __forceinline__ float lane_bcast(float v, int j) {
    return __builtin_bit_cast(float, __builtin_amdgcn_readlane(__builtin_bit_cast(int, v), j));
}
__device__ __forceinline__ int lane_bcast_i(int v, int j) {
    return __builtin_amdgcn_readlane(v, j);
}

// ---------------- CSR build ----------------
__global__ void k_hist(const int* __restrict__ dst, unsigned* __restrict__ cur, int E) {
    int e = blockIdx.x * blockDim.x + threadIdx.x;
    if (e < E) atomicAdd(&cur[dst[e]], 1u);
}

// 3-pass hierarchical exclusive scan of cur[0..n) -> off[0..n], cur := off copy
#define SCAN_B 256
__global__ void __launch_bounds__(256) k_scanA(const unsigned* __restrict__ cur,
                                               unsigned* __restrict__ bsum, int n, int chunk) {
    const int lo = blockIdx.x * chunk, hi = min(lo + chunk, n);
    unsigned s = 0;
    for (int i = lo + threadIdx.x; i < hi; i += 256) s += cur[i];
    __shared__ unsigned wpart[4];
    const int lane = threadIdx.x & 63, wid = threadIdx.x >> 6;
    s = wsum_u(s);
    if (lane == 0) wpart[wid] = s;
    __syncthreads();
    if (threadIdx.x == 0) bsum[blockIdx.x] = wpart[0] + wpart[1] + wpart[2] + wpart[3];
}

__global__ void __launch_bounds__(256) k_scanB(unsigned* __restrict__ bsum,
                                               unsigned* __restrict__ off, int n) {
    __shared__ unsigned wpart[4];
    const int t = threadIdx.x, lane = t & 63, wid = t >> 6;
    unsigned v = bsum[t];
    unsigned inc = wave_iscan(v, lane);
    if (lane == 63) wpart[wid] = inc;
    __syncthreads();
    unsigned wo = 0;
    for (int i = 0; i < wid; ++i) wo += wpart[i];
    bsum[t] = wo + inc - v;                 // exclusive prefix
    if (t == 255) off[n] = wo + inc;        // grand total
}

__global__ void __launch_bounds__(256) k_scanC(unsigned* __restrict__ cur,
                                               const unsigned* __restrict__ bsum,
                                               unsigned* __restrict__ off, int n, int chunk) {
    const int lo = blockIdx.x * chunk, hi = min(lo + chunk, n);
    const int t = threadIdx.x, lane = t & 63, wid = t >> 6;
    const int S = (chunk + 255) >> 8;
    const int a = lo + t * S, b = min(a + S, hi);
    unsigned c[4];
    unsigned segsum = 0;
#pragma unroll
    for (int s = 0; s < 4; ++s) {
        int i = a + s;
        unsigned v = (s < S && i < b) ? cur[i] : 0u;
        c[s] = v; segsum += v;
    }
    __shared__ unsigned wpart[4];
    unsigned inc = wave_iscan(segsum, lane);
    if (lane == 63) wpart[wid] = inc;
    __syncthreads();
    unsigned wo = 0;
    for (int i = 0; i < wid; ++i) wo += wpart[i];
    unsigned run = bsum[blockIdx.x] + wo + inc - segsum;
#pragma unroll
    for (int s = 0; s < 4; ++s) {
        int i = a + s;
        if (s < S && i < b) { off[i] = run; cur[i] = run; run += c[s]; }
    }
}

// fill sorted-by-dst combined edge meta {src, w_bits} (single 8B scatter per edge)
__global__ void k_fill(const int* __restrict__ dst, const int* __restrict__ src,
                       const float* __restrict__ ew, unsigned* __restrict__ cur,
                       int2* __restrict__ meta, int E) {
    int e = blockIdx.x * blockDim.x + threadIdx.x;
    if (e < E) {
        unsigned slot = atomicAdd(&cur[dst[e]], 1u);
        meta[slot] = make_int2(src[e], __float_as_int(ew[e]));
    }
}

// ---------------- hyperbolic biases (both in one launch) ----------------
__global__ void k_hb2(const float* __restrict__ b0, float* __restrict__ hb0,
                      const float* __restrict__ b1, float* __restrict__ hb1) {
    const float* b  = blockIdx.x ? b1 : b0;
    float* hb       = blockIdx.x ? hb1 : hb0;
    int lane = threadIdx.x & 63;
    float u = b[lane];
    float n = sqrtf(fmaxf(wsum(u * u), MIN_NORM));
    float t = tanhf(n);
    float h = t * u / n;
    float hn = sqrtf(fmaxf(wsum(h * h), MIN_NORM));
    if (hn > MAXNORM) h *= MAXNORM / hn;
    hb[lane] = h;
    float y2 = wsum(h * h);
    if (lane == 0) hb[64] = y2;
}

// post-matvec tail for TWO nodes, interleaved reductions.
// res = f*mx with f = clamp(tanh(mxn/xn*artanh(xn)))/mxn; xy = f*sum(mx*hb).
__device__ __forceinline__ void post_linear2(float mx0, float mx1, float xn0, float xn1,
                                             float hbv, float y2, float& r0, float& r1) {
    float a0 = mx0 * mx0, b0 = mx0 * hbv;
    float a1 = mx1 * mx1, b1 = mx1 * hbv;
#pragma unroll
    for (int m = 32; m >= 1; m >>= 1) {
        a0 += __shfl_xor(a0, m, 64);
        b0 += __shfl_xor(b0, m, 64);
        a1 += __shfl_xor(a1, m, 64);
        b1 += __shfl_xor(b1, m, 64);
    }
    float mxn0 = sqrtf(fmaxf(a0, MIN_NORM));
    float mxn1 = sqrtf(fmaxf(a1, MIN_NORM));
    float tt0 = tanhf(mxn0 / xn0 * artanh_f(xn0));
    float tt1 = tanhf(mxn1 / xn1 * artanh_f(xn1));
    float rn0 = fminf(tt0, MAXNORM), rn1 = fminf(tt1, MAXNORM);
    float f0 = rn0 / mxn0, f1 = rn1 / mxn1;
    float xy0 = f0 * b0, xy1 = f1 * b1;
    float x20 = rn0 * rn0, x21 = rn1 * rn1;
    float k0 = 1.f + 2.f * xy0 + y2, k1 = 1.f + 2.f * xy1 + y2;
    float den0 = 1.f + 2.f * xy0 + x20 * y2;
    float den1 = 1.f + 2.f * xy1 + x21 * y2;
    float i0 = 1.f / fmaxf(den0, MIN_NORM), i1 = 1.f / fmaxf(den1, MIN_NORM);
    float o0 = (k0 * f0 * mx0 + (1.f - x20) * hbv) * i0;
    float o1 = (k1 * f1 * mx1 + (1.f - x21) * hbv) * i1;
    float s0 = o0 * o0, s1 = o1 * o1;
#pragma unroll
    for (int m = 32; m >= 1; m >>= 1) {
        s0 += __shfl_xor(s0, m, 64);
        s1 += __shfl_xor(s1, m, 64);
    }
    float on0 = sqrtf(fmaxf(s0, MIN_NORM));
    float on1 = sqrtf(fmaxf(s1, MIN_NORM));
    float g0 = on0 > MAXNORM ? MAXNORM / on0 : 1.f;
    float g1 = on1 > MAXNORM ? MAXNORM / on1 : 1.f;
    float cn0 = fminf(on0, MAXNORM), cn1 = fminf(on1, MAXNORM);
    r0 = artanh_f(cn0) * g0 * o0 / cn0;
    r1 = artanh_f(cn1) * g1 * o1 / cn1;
}

// fused: [encode ->] mobius_matvec(W) -> +hyp_b -> proj -> logmap0
template <bool ENCODE>
__global__ void __launch_bounds__(256, 2) k_lin(const float* __restrict__ xin,
                                                const float* __restrict__ W,
                                                const float* __restrict__ hb,
                                                float* __restrict__ xt_out, int nNodes) {
    const int lane = threadIdx.x & 63, wid = threadIdx.x >> 6;
    float wreg[64];
    {
        const float4* wr = (const float4*)(W + (size_t)lane * 64);
#pragma unroll
        for (int q = 0; q < 16; ++q) {
            float4 v = wr[q];
            wreg[q * 4 + 0] = v.x; wreg[q * 4 + 1] = v.y;
            wreg[q * 4 + 2] = v.z; wreg[q * 4 + 3] = v.w;
        }
    }
    const float hbv = hb[lane];
    const float y2  = hb[64];

    const int gw = blockIdx.x * 4 + wid;
    const int nw = gridDim.x * 4;
    for (int base = gw * 2; base < nNodes; base += nw * 2) {
        const bool has1 = (base + 1) < nNodes;
        float u0 = xin[(size_t)base * 64 + lane];
        float u1 = has1 ? xin[(size_t)(base + 1) * 64 + lane] : 0.f;
        // interleaved norm reductions for both nodes
        float s0 = u0 * u0, s1 = u1 * u1;
#pragma unroll
        for (int m = 32; m >= 1; m >>= 1) {
            s0 += __shfl_xor(s0, m, 64);
            s1 += __shfl_xor(s1, m, 64);
        }
        float xn0, xn1;
        if (ENCODE) {
            float n0 = sqrtf(fmaxf(s0, MIN_NORM));
            float n1 = sqrtf(fmaxf(s1, MIN_NORM));
            float t0 = tanhf(n0), t1 = tanhf(n1);
            u0 = t0 * u0 / n0;
            u1 = t1 * u1 / n1;
            if (t0 > MAXNORM) { u0 *= MAXNORM / t0; t0 = MAXNORM; }
            if (t1 > MAXNORM) { u1 *= MAXNORM / t1; t1 = MAXNORM; }
            xn0 = t0; xn1 = t1;
        } else {
            xn0 = sqrtf(fmaxf(s0, MIN_NORM));
            xn1 = sqrtf(fmaxf(s1, MIN_NORM));
        }
        float a0e = 0.f, a0o = 0.f, a1e = 0.f, a1o = 0.f;
#pragma unroll
        for (int j = 0; j < 64; j += 2) {
            a0e = fmaf(lane_bcast(u0, j),     wreg[j],     a0e);
            a0o = fmaf(lane_bcast(u0, j + 1), wreg[j + 1], a0o);
            a1e = fmaf(lane_bcast(u1, j),     wreg[j],     a1e);
            a1o = fmaf(lane_bcast(u1, j + 1), wreg[j + 1], a1o);
        }
        float mx0 = a0e + a0o, mx1 = a1e + a1o;
        float r0, r1;
        post_linear2(mx0, mx1, xn0, xn1, hbv, y2, r0, r1);
        xt_out[(size_t)base * 64 + lane] = r0;
        if (has1) xt_out[(size_t)(base + 1) * 64 + lane] = r1;
    }
}

// CSR gather-aggregate: meta preloaded cooperatively, broadcast via readlane,
// 4-deep gather pipeline, 2 accumulator chains. Tail math fused.
__global__ void __launch_bounds__(256) k_agg(const float* __restrict__ xt,
                                             const int2* __restrict__ meta,
                                             const unsigned* __restrict__ off,
                                             float* __restrict__ hout, int nNodes) {
    const int lane = threadIdx.x & 63, wid = threadIdx.x >> 6;
    int gw = blockIdx.x * (blockDim.x >> 6) + wid;
    int nw = gridDim.x * (blockDim.x >> 6);
    for (int node = gw; node < nNodes; node += nw) {
        unsigned s0 = off[node], s1 = off[node + 1];
        int deg = (int)(s1 - s0);
        // cooperative meta preload: lane L holds edge s0+L
        int2 m = make_int2(0, 0);
        if (lane < deg) m = meta[s0 + lane];
        int kmax = min(deg, 64);
        float acc0 = 0.f, acc1 = 0.f;
        int k = 0;
        for (; k + 4 <= kmax; k += 4) {
            int sn0 = lane_bcast_i(m.x, k);
            int sn1 = lane_bcast_i(m.x, k + 1);
            int sn2 = lane_bcast_i(m.x, k + 2);
            int sn3 = lane_bcast_i(m.x, k + 3);
            float w0 = lane_bcast(__int_as_float(m.y), k);
            float w1 = lane_bcast(__int_as_float(m.y), k + 1);
            float w2 = lane_bcast(__int_as_float(m.y), k + 2);
            float w3 = lane_bcast(__int_as_float(m.y), k + 3);
            float v0 = xt[(size_t)sn0 * 64 + lane];
            float v1 = xt[(size_t)sn1 * 64 + lane];
            float v2 = xt[(size_t)sn2 * 64 + lane];
            float v3 = xt[(size_t)sn3 * 64 + lane];
            acc0 = fmaf(v0, w0, acc0);
            acc1 = fmaf(v1, w1, acc1);
            acc0 = fmaf(v2, w2, acc0);
            acc1 = fmaf(v3, w3, acc1);
        }
        for (; k < kmax; ++k) {
            int sn = lane_bcast_i(m.x, k);
            float wv = lane_bcast(__int_as_float(m.y), k);
            acc0 = fmaf(xt[(size_t)sn * 64 + lane], wv, acc0);
        }
        // rare tail: degree > 64 (uniform loads)
        for (unsigned kk = s0 + 64; kk < s1; ++kk) {
            int2 mm = meta[kk];
            acc1 = fmaf(xt[(size_t)mm.x * 64 + lane], __int_as_float(mm.y), acc1);
        }
        float acc = acc0 + acc1;
        // expmap0 + proj (norm after scaling = tanh(n))
        float n = sqrtf(fmaxf(wsum(acc * acc), MIN_NORM));
        float t = tanhf(n);
        float p = t * acc / n;
        float pn = t;
        if (pn > MAXNORM) { p *= MAXNORM / pn; pn = MAXNORM; }
        // hyp_act: relu in tangent space
        float xv = artanh_f(pn) * p / pn;
        xv = fmaxf(xv, 0.f);
        // expmap0 + proj (norm = tanh(m))
        float mm = sqrtf(fmaxf(wsum(xv * xv), MIN_NORM));
        float t2 = tanhf(mm);
        float q = t2 * xv / mm;
        float qn = t2;
        if (qn > MAXNORM) q *= MAXNORM / qn;
        hout[(size_t)node * 64 + lane] = q;
    }
}

extern "C" void kernel_launch(void* const* d_in, const int* in_sizes, int n_in,
                              void* d_out, int out_size, void* d_ws, size_t ws_size,
                              hipStream_t stream) {
    const float* x   = (const float*)d_in[0];
    const int*   ei  = (const int*)d_in[1];
    const float* ew  = (const float*)d_in[2];
    const float* W0  = (const float*)d_in[3];
    const float* b0  = (const float*)d_in[4];
    const float* W1  = (const float*)d_in[5];
    const float* b1  = (const float*)d_in[6];
    const int N = in_sizes[0] / 64;
    const int E = in_sizes[2];
    const int* src = ei;
    const int* dst = ei + E;

    uint8_t* p = (uint8_t*)d_ws;
    auto carve = [&](size_t bytes) { uint8_t* q = p; p += (bytes + 255) & ~(size_t)255; return q; };
    unsigned* off  = (unsigned*)carve((size_t)(N + 1) * 4);
    unsigned* cur  = (unsigned*)carve((size_t)N * 4);
    unsigned* bsum = (unsigned*)carve((size_t)SCAN_B * 4);
    int2*     meta = (int2*)carve((size_t)E * 8);
    float* hb0 = (float*)carve(65 * 4);
    float* hb1 = (float*)carve(65 * 4);
    float* xt  = (float*)carve((size_t)N * 64 * 4);
    float* hbuf = (float*)d_out;

    const int chunk = (N + SCAN_B - 1) / SCAN_B;

    // CSR build (sorted-by-dst combined meta)
    hipMemsetAsync(cur, 0, (size_t)N * 4, stream);
    k_hist<<<(E + 255) / 256, 256, 0, stream>>>(dst, cur, E);
    k_scanA<<<SCAN_B, 256, 0, stream>>>(cur, bsum, N, chunk);
    k_scanB<<<1, 256, 0, stream>>>(bsum, off, N);
    k_scanC<<<SCAN_B, 256, 0, stream>>>(cur, bsum, off, N, chunk);
    k_fill<<<(E + 255) / 256, 256, 0, stream>>>(dst, src, ew, cur, meta, E);

    k_hb2<<<2, 64, 0, stream>>>(b0, hb0, b1, hb1);

    // layer 0
    k_lin<true><<<2048, 256, 0, stream>>>(x, W0, hb0, xt, N);
    k_agg<<<2048, 256, 0, stream>>>(xt, meta, off, hbuf, N);
    // layer 1
    k_lin<false><<<2048, 256, 0, stream>>>(hbuf, W1, hb1, xt, N);
    k_agg<<<2048, 256, 0, stream>>>(xt, meta, off, (float*)d_out, N);
}

// Round 5
// 437.540 us; speedup vs baseline: 4.0173x; 1.4192x over previous
//
#include <hip/hip_runtime.h>
#include <hip/hip_bf16.h>
#include <stdint.h>

#define MIN_NORM 1e-15f
#define MAXNORM 0.996f          // (1 - 4e-3)/sqrt(1)
#define ART_CLIP 0.9999999f     // 1 - 1e-7

__device__ __forceinline__ float rcp_f(float x) { return __builtin_amdgcn_rcpf(x); }
__device__ __forceinline__ float rsq_f(float x) { return __builtin_amdgcn_rsqf(x); }

// tanh(x) for x >= 0:  1 - 2/(e^{2x}+1); e^inf -> inf -> rcp -> 0 -> 1 (graceful)
__device__ __forceinline__ float fast_tanh(float x) {
    float e = __expf(2.f * x);
    return 1.f - 2.f * rcp_f(e + 1.f);
}
// artanh(x) for 0 <= x (clipped to ART_CLIP): 0.5*ln((1+x)/(1-x))
__device__ __forceinline__ float fast_artanh(float x) {
    x = fminf(x, ART_CLIP);
    return 0.5f * __logf((1.f + x) * rcp_f(1.f - x));
}

__device__ __forceinline__ float wsum(float v) {
#pragma unroll
    for (int m = 32; m >= 1; m >>= 1) v += __shfl_xor(v, m, 64);
    return v;
}
__device__ __forceinline__ unsigned wsum_u(unsigned v) {
#pragma unroll
    for (int m = 32; m >= 1; m >>= 1) v += __shfl_xor(v, m, 64);
    return v;
}
__device__ __forceinline__ unsigned wave_iscan(unsigned v, int lane) {
#pragma unroll
    for (int d = 1; d < 64; d <<= 1) {
        unsigned o = __shfl_up(v, d, 64);
        if (lane >= d) v += o;
    }
    return v;
}
__device__ __forceinline__ float lane_bcast(float v, int j) {
    return __builtin_bit_cast(float, __builtin_amdgcn_readlane(__builtin_bit_cast(int, v), j));
}
__device__ __forceinline__ int lane_bcast_i(int v, int j) {
    return __builtin_amdgcn_readlane(v, j);
}

// ---------------- CSR build ----------------
__global__ void k_hist(const int* __restrict__ dst, unsigned* __restrict__ cur, int E) {
    int e = blockIdx.x * blockDim.x + threadIdx.x;
    if (e < E) atomicAdd(&cur[dst[e]], 1u);
}

#define SCAN_B 256
__global__ void __launch_bounds__(256) k_scanA(const unsigned* __restrict__ cur,
                                               unsigned* __restrict__ bsum, int n, int chunk) {
    const int lo = blockIdx.x * chunk, hi = min(lo + chunk, n);
    unsigned s = 0;
    for (int i = lo + threadIdx.x; i < hi; i += 256) s += cur[i];
    __shared__ unsigned wpart[4];
    const int lane = threadIdx.x & 63, wid = threadIdx.x >> 6;
    s = wsum_u(s);
    if (lane == 0) wpart[wid] = s;
    __syncthreads();
    if (threadIdx.x == 0) bsum[blockIdx.x] = wpart[0] + wpart[1] + wpart[2] + wpart[3];
}

__global__ void __launch_bounds__(256) k_scanB(unsigned* __restrict__ bsum,
                                               unsigned* __restrict__ off, int n) {
    __shared__ unsigned wpart[4];
    const int t = threadIdx.x, lane = t & 63, wid = t >> 6;
    unsigned v = bsum[t];
    unsigned inc = wave_iscan(v, lane);
    if (lane == 63) wpart[wid] = inc;
    __syncthreads();
    unsigned wo = 0;
    for (int i = 0; i < wid; ++i) wo += wpart[i];
    bsum[t] = wo + inc - v;
    if (t == 255) off[n] = wo + inc;
}

__global__ void __launch_bounds__(256) k_scanC(unsigned* __restrict__ cur,
                                               const unsigned* __restrict__ bsum,
                                               unsigned* __restrict__ off, int n, int chunk) {
    const int lo = blockIdx.x * chunk, hi = min(lo + chunk, n);
    const int t = threadIdx.x, lane = t & 63, wid = t >> 6;
    const int S = (chunk + 255) >> 8;
    const int a = lo + t * S, b = min(a + S, hi);
    unsigned c[4];
    unsigned segsum = 0;
#pragma unroll
    for (int s = 0; s < 4; ++s) {
        int i = a + s;
        unsigned v = (s < S && i < b) ? cur[i] : 0u;
        c[s] = v; segsum += v;
    }
    __shared__ unsigned wpart[4];
    unsigned inc = wave_iscan(segsum, lane);
    if (lane == 63) wpart[wid] = inc;
    __syncthreads();
    unsigned wo = 0;
    for (int i = 0; i < wid; ++i) wo += wpart[i];
    unsigned run = bsum[blockIdx.x] + wo + inc - segsum;
#pragma unroll
    for (int s = 0; s < 4; ++s) {
        int i = a + s;
        if (s < S && i < b) { off[i] = run; cur[i] = run; run += c[s]; }
    }
}

__global__ void k_fill(const int* __restrict__ dst, const int* __restrict__ src,
                       const float* __restrict__ ew, unsigned* __restrict__ cur,
                       int2* __restrict__ meta, int E) {
    int e = blockIdx.x * blockDim.x + threadIdx.x;
    if (e < E) {
        unsigned slot = atomicAdd(&cur[dst[e]], 1u);
        meta[slot] = make_int2(src[e], __float_as_int(ew[e]));
    }
}

// ---------------- hyperbolic biases ----------------
__global__ void k_hb2(const float* __restrict__ b0, float* __restrict__ hb0,
                      const float* __restrict__ b1, float* __restrict__ hb1) {
    const float* b  = blockIdx.x ? b1 : b0;
    float* hb       = blockIdx.x ? hb1 : hb0;
    int lane = threadIdx.x & 63;
    float u = b[lane];
    float n = sqrtf(fmaxf(wsum(u * u), MIN_NORM));
    float t = tanhf(n);
    float h = t * u / n;
    float hn = sqrtf(fmaxf(wsum(h * h), MIN_NORM));
    if (hn > MAXNORM) h *= MAXNORM / hn;
    hb[lane] = h;
    float y2 = wsum(h * h);
    if (lane == 0) hb[64] = y2;
}

// per-node scalar chain: given n2=||x||^2, m2=||Wx||^2, d=<Wx,hb>, y2=||hb||^2,
// produce lambda, mu with  xt = lambda*(Wx) + mu*hb
template <bool ENCODE>
__device__ __forceinline__ void lin_scalars(float n2, float m2, float d, float y2,
                                            float& lam, float& mu) {
    float nx = sqrtf(fmaxf(n2, MIN_NORM));
    float xn = ENCODE ? fminf(fast_tanh(nx), MAXNORM) : nx;
    float sm = sqrtf(fmaxf(m2, MIN_NORM));
    float ratio = sm * rcp_f(nx);
    float tt = fminf(fast_tanh(ratio * fast_artanh(xn)), MAXNORM);
    float rho = tt * rcp_f(sm);          // res = rho * M ; ||res|| = tt
    float xy = rho * d;
    float x2 = tt * tt;
    float den = fmaxf(1.f + 2.f * xy + x2 * y2, MIN_NORM);
    float iden = rcp_f(den);
    float A = (1.f + 2.f * xy + y2) * iden;   // o = A*res + B*hb
    float B = (1.f - x2) * iden;
    float on2 = A * A * x2 + 2.f * A * B * xy + B * B * y2;   // ||o||^2 analytic
    float on = sqrtf(fmaxf(on2, MIN_NORM));
    float g = on > MAXNORM ? MAXNORM * rcp_f(on) : 1.f;
    float onc = fminf(on, MAXNORM);
    float L = fast_artanh(onc) * rcp_f(onc) * g;              // logmap0 scale
    lam = L * A * rho;
    mu  = L * B;
}

// fused: matvec on RAW input (encode scale cancels) -> lambda/mu tail
template <bool ENCODE>
__global__ void __launch_bounds__(256, 2) k_lin(const float* __restrict__ xin,
                                                const float* __restrict__ W,
                                                const float* __restrict__ hb,
                                                float* __restrict__ xt_out, int nNodes) {
    const int lane = threadIdx.x & 63, wid = threadIdx.x >> 6;
    // W row in 16 named float4s (no array -> guaranteed register residency)
    const float4* wr = (const float4*)(W + (size_t)lane * 64);
    float4 w0 = wr[0], w1 = wr[1], w2 = wr[2], w3 = wr[3];
    float4 w4 = wr[4], w5 = wr[5], w6 = wr[6], w7 = wr[7];
    float4 w8 = wr[8], w9 = wr[9], w10 = wr[10], w11 = wr[11];
    float4 w12 = wr[12], w13 = wr[13], w14 = wr[14], w15 = wr[15];
    const float hbv = hb[lane];
    const float y2  = hb[64];

    const int gw = blockIdx.x * 4 + wid;
    const int nw = gridDim.x * 4;
    for (int base = gw * 2; base < nNodes; base += nw * 2) {
        const bool has1 = (base + 1) < nNodes;
        float u0 = xin[(size_t)base * 64 + lane];
        float u1 = has1 ? xin[(size_t)(base + 1) * 64 + lane] : 0.f;
        float a0e = 0.f, a0o = 0.f, a1e = 0.f, a1o = 0.f;
#define MSTEP(WQ, J)                                      \
        a0e = fmaf(lane_bcast(u0, J),     WQ.x, a0e);     \
        a0o = fmaf(lane_bcast(u0, J + 1), WQ.y, a0o);     \
        a1e = fmaf(lane_bcast(u1, J),     WQ.x, a1e);     \
        a1o = fmaf(lane_bcast(u1, J + 1), WQ.y, a1o);     \
        a0e = fmaf(lane_bcast(u0, J + 2), WQ.z, a0e);     \
        a0o = fmaf(lane_bcast(u0, J + 3), WQ.w, a0o);     \
        a1e = fmaf(lane_bcast(u1, J + 2), WQ.z, a1e);     \
        a1o = fmaf(lane_bcast(u1, J + 3), WQ.w, a1o);
        MSTEP(w0, 0)   MSTEP(w1, 4)   MSTEP(w2, 8)   MSTEP(w3, 12)
        MSTEP(w4, 16)  MSTEP(w5, 20)  MSTEP(w6, 24)  MSTEP(w7, 28)
        MSTEP(w8, 32)  MSTEP(w9, 36)  MSTEP(w10, 40) MSTEP(w11, 44)
        MSTEP(w12, 48) MSTEP(w13, 52) MSTEP(w14, 56) MSTEP(w15, 60)
#undef MSTEP
        float M0 = a0e + a0o, M1 = a1e + a1o;
        // single interleaved reduction tree: 6 values
        float n20 = u0 * u0, m20 = M0 * M0, d0 = M0 * hbv;
        float n21 = u1 * u1, m21 = M1 * M1, d1 = M1 * hbv;
#pragma unroll
        for (int m = 32; m >= 1; m >>= 1) {
            n20 += __shfl_xor(n20, m, 64);
            m20 += __shfl_xor(m20, m, 64);
            d0  += __shfl_xor(d0,  m, 64);
            n21 += __shfl_xor(n21, m, 64);
            m21 += __shfl_xor(m21, m, 64);
            d1  += __shfl_xor(d1,  m, 64);
        }
        float lam0, mu0, lam1, mu1;
        lin_scalars<ENCODE>(n20, m20, d0, y2, lam0, mu0);
        lin_scalars<ENCODE>(n21, m21, d1, y2, lam1, mu1);
        xt_out[(size_t)base * 64 + lane] = fmaf(lam0, M0, mu0 * hbv);
        if (has1)
            xt_out[(size_t)(base + 1) * 64 + lane] = fmaf(lam1, M1, mu1 * hbv);
    }
}

// CSR gather-aggregate; tail folded to hout = gamma * relu(acc)
__global__ void __launch_bounds__(256) k_agg(const float* __restrict__ xt,
                                             const int2* __restrict__ meta,
                                             const unsigned* __restrict__ off,
                                             float* __restrict__ hout, int nNodes) {
    const int lane = threadIdx.x & 63, wid = threadIdx.x >> 6;
    int gw = blockIdx.x * (blockDim.x >> 6) + wid;
    int nw = gridDim.x * (blockDim.x >> 6);
    for (int node = gw; node < nNodes; node += nw) {
        unsigned s0 = off[node], s1 = off[node + 1];
        int deg = (int)(s1 - s0);
        int2 m = make_int2(0, 0);
        if (lane < deg) m = meta[s0 + lane];
        int kmax = min(deg, 64);
        float acc0 = 0.f, acc1 = 0.f;
        int k = 0;
        for (; k + 4 <= kmax; k += 4) {
            int sn0 = lane_bcast_i(m.x, k);
            int sn1 = lane_bcast_i(m.x, k + 1);
            int sn2 = lane_bcast_i(m.x, k + 2);
            int sn3 = lane_bcast_i(m.x, k + 3);
            float w0 = lane_bcast(__int_as_float(m.y), k);
            float w1 = lane_bcast(__int_as_float(m.y), k + 1);
            float w2 = lane_bcast(__int_as_float(m.y), k + 2);
            float w3 = lane_bcast(__int_as_float(m.y), k + 3);
            float v0 = xt[(size_t)sn0 * 64 + lane];
            float v1 = xt[(size_t)sn1 * 64 + lane];
            float v2 = xt[(size_t)sn2 * 64 + lane];
            float v3 = xt[(size_t)sn3 * 64 + lane];
            acc0 = fmaf(v0, w0, acc0);
            acc1 = fmaf(v1, w1, acc1);
            acc0 = fmaf(v2, w2, acc0);
            acc1 = fmaf(v3, w3, acc1);
        }
        for (; k < kmax; ++k) {
            int sn = lane_bcast_i(m.x, k);
            float wv = lane_bcast(__int_as_float(m.y), k);
            acc0 = fmaf(xt[(size_t)sn * 64 + lane], wv, acc0);
        }
        for (unsigned kk = s0 + 64; kk < s1; ++kk) {
            int2 mm = meta[kk];
            acc1 = fmaf(xt[(size_t)mm.x * 64 + lane], __int_as_float(mm.y), acc1);
        }
        float acc = acc0 + acc1;
        float r = fmaxf(acc, 0.f);
        // one interleaved tree: ||acc||^2 and ||relu(acc)||^2
        float sA = acc * acc, sR = r * r;
#pragma unroll
        for (int mm = 32; mm >= 1; mm >>= 1) {
            sA += __shfl_xor(sA, mm, 64);
            sR += __shfl_xor(sR, mm, 64);
        }
        float n = sqrtf(fmaxf(sA, MIN_NORM));
        float t = fast_tanh(n);
        float g1 = t > MAXNORM ? MAXNORM * rcp_f(t) : 1.f;
        float tc = fminf(t, MAXNORM);
        // xv = alpha * relu(acc)
        float alpha = fast_artanh(tc) * rcp_f(tc) * g1 * t * rcp_f(n);
        float mnorm = sqrtf(fmaxf(alpha * alpha * sR, MIN_NORM));
        float t2 = fast_tanh(mnorm);
        float g2 = t2 > MAXNORM ? MAXNORM * rcp_f(t2) : 1.f;
        float gamma = t2 * rcp_f(mnorm) * g2 * alpha;
        hout[(size_t)node * 64 + lane] = gamma * r;
    }
}

extern "C" void kernel_launch(void* const* d_in, const int* in_sizes, int n_in,
                              void* d_out, int out_size, void* d_ws, size_t ws_size,
                              hipStream_t stream) {
    const float* x   = (const float*)d_in[0];
    const int*   ei  = (const int*)d_in[1];
    const float* ew  = (const float*)d_in[2];
    const float* W0  = (const float*)d_in[3];
    const float* b0  = (const float*)d_in[4];
    const float* W1  = (const float*)d_in[5];
    const float* b1  = (const float*)d_in[6];
    const int N = in_sizes[0] / 64;
    const int E = in_sizes[2];
    const int* src = ei;
    const int* dst = ei + E;

    uint8_t* p = (uint8_t*)d_ws;
    auto carve = [&](size_t bytes) { uint8_t* q = p; p += (bytes + 255) & ~(size_t)255; return q; };
    unsigned* off  = (unsigned*)carve((size_t)(N + 1) * 4);
    unsigned* cur  = (unsigned*)carve((size_t)N * 4);
    unsigned* bsum = (unsigned*)carve((size_t)SCAN_B * 4);
    int2*     meta = (int2*)carve((size_t)E * 8);
    float* hb0 = (float*)carve(65 * 4);
    float* hb1 = (float*)carve(65 * 4);
    float* xt  = (float*)carve((size_t)N * 64 * 4);
    float* hbuf = (float*)d_out;

    const int chunk = (N + SCAN_B - 1) / SCAN_B;

    hipMemsetAsync(cur, 0, (size_t)N * 4, stream);
    k_hist<<<(E + 255) / 256, 256, 0, stream>>>(dst, cur, E);
    k_scanA<<<SCAN_B, 256, 0, stream>>>(cur, bsum, N, chunk);
    k_scanB<<<1, 256, 0, stream>>>(bsum, off, N);
    k_scanC<<<SCAN_B, 256, 0, stream>>>(cur, bsum, off, N, chunk);
    k_fill<<<(E + 255) / 256, 256, 0, stream>>>(dst, src, ew, cur, meta, E);

    k_hb2<<<2, 64, 0, stream>>>(b0, hb0, b1, hb1);

    // layer 0
    k_lin<true><<<2048, 256, 0, stream>>>(x, W0, hb0, xt, N);
    k_agg<<<2048, 256, 0, stream>>>(xt, meta, off, hbuf, N);
    // layer 1
    k_lin<false><<<2048, 256, 0, stream>>>(hbuf, W1, hb1, xt, N);
    k_agg<<<2048, 256, 0, stream>>>(xt, meta, off, (float*)d_out, N);
}